// Round 9
// baseline (116.572 us; speedup 1.0000x reference)
//
#include <hip/hip_runtime.h>

typedef __attribute__((ext_vector_type(8))) __bf16 bf16x8;
typedef __attribute__((ext_vector_type(16))) float f32x16;
typedef __attribute__((ext_vector_type(4))) float f32x4;
typedef __attribute__((ext_vector_type(4))) unsigned short us4;

__device__ __forceinline__ unsigned short f2bf(float f) {
  __bf16 h = (__bf16)f;  // native RNE convert
  return __builtin_bit_cast(unsigned short, h);
}
__device__ __forceinline__ unsigned pack2bf(float lo, float hi) {
  return (unsigned)f2bf(lo) | ((unsigned)f2bf(hi) << 16);
}

#define GLL(src, dst)                                                            \
  __builtin_amdgcn_global_load_lds((const __attribute__((address_space(1))) void*)(src), \
                                   (__attribute__((address_space(3))) void*)(dst), 16, 0, 0)

// Stage a [rows x 64] bf16 tile (row-major, row stride = ld elements in global)
// into LDS with 16B-chunk XOR swizzle: LDS(row, kc) = G(row, kc ^ (row&7)).
__device__ __forceinline__ void stage_chunks(const unsigned short* g, int ld,
                                             unsigned short* lds, int rows, int tid) {
  int total = rows * 8;  // 16B chunks
  for (int c0 = 0; c0 < total; c0 += 256) {
    int c = c0 + tid;
    int row = c >> 3, kc = c & 7;
    const unsigned short* src = g + (size_t)row * ld + ((kc ^ (row & 7)) << 3);
    unsigned short* dst = lds + (size_t)(c0 + (tid & 192)) * 8;  // wave-uniform base
    GLL(src, dst);
  }
}

// Read one MFMA fragment (8 contiguous bf16 = 16B) from a swizzled [*x64] tile.
__device__ __forceinline__ bf16x8 frag(const unsigned short* lds, int row, int kc) {
  return *(const bf16x8*)(lds + row * 64 + ((kc ^ (row & 7)) << 3));
}

// ---------------- converts / transpose ----------------

__global__ void k_cvt(const float* __restrict__ in, unsigned short* __restrict__ outp, int n) {
  int i = (blockIdx.x * 256 + threadIdx.x) * 4;
  if (i + 3 < n) {
    f32x4 v = *(const f32x4*)(in + i);
    us4 o;
#pragma unroll
    for (int k = 0; k < 4; k++) o[k] = f2bf(v[k]);
    *(us4*)(outp + i) = o;
  }
}

// xT[b][n][c] = x[b][c][n], fp32 -> bf16
__global__ __launch_bounds__(256) void k_xpose(const float* __restrict__ x,
                                               unsigned short* __restrict__ xT) {
  __shared__ float t[32][33];
  int tid = threadIdx.x;
  int col = tid & 31, rowb = tid >> 5;
  int nt = blockIdx.x * 32, ct = blockIdx.y * 32, b = blockIdx.z;
  const float* src = x + ((size_t)b * 256 + ct) * 2304 + nt;
#pragma unroll
  for (int rr = 0; rr < 32; rr += 8) t[rowb + rr][col] = src[(size_t)(rowb + rr) * 2304 + col];
  __syncthreads();
  unsigned short* dst = xT + ((size_t)b * 2304 + nt) * 256 + ct;
#pragma unroll
  for (int rr = 0; rr < 32; rr += 8) dst[(size_t)(rowb + rr) * 256 + col] = f2bf(t[col][rowb + rr]);
}

// ---------------- GEMM1: qkv = Wqkv * x ----------------
// q is pre-scaled by 0.125 * log2(e) so attention can use exp2 directly.
__global__ __launch_bounds__(256, 2) void k_gemm_qkv(
    const unsigned short* __restrict__ W, const unsigned short* __restrict__ xT,
    unsigned short* __restrict__ qT, unsigned short* __restrict__ kT,
    unsigned short* __restrict__ vv) {
  __shared__ unsigned short As[128 * 64];
  __shared__ unsigned short Bs[128 * 64];
  int tid = threadIdx.x, lane = tid & 63, wid = tid >> 6;
  int m0 = blockIdx.x * 128, n0 = blockIdx.y * 128, b = blockIdx.z;
  const unsigned short* Ag = W + (size_t)m0 * 256;
  const unsigned short* Bg = xT + ((size_t)b * 2304 + n0) * 256;
  int wm = (wid >> 1) * 64, wn = (wid & 1) * 64;
  f32x4 acc[4][4] = {};
  for (int kt = 0; kt < 256; kt += 64) {
    __syncthreads();
    stage_chunks(Ag + kt, 256, As, 128, tid);
    stage_chunks(Bg + kt, 256, Bs, 128, tid);
    __syncthreads();
#pragma unroll
    for (int kk = 0; kk < 2; kk++) {
      bf16x8 af[4], bf[4];
#pragma unroll
      for (int i = 0; i < 4; i++) af[i] = frag(As, wm + i * 16 + (lane & 15), kk * 4 + (lane >> 4));
#pragma unroll
      for (int j = 0; j < 4; j++) bf[j] = frag(Bs, wn + j * 16 + (lane & 15), kk * 4 + (lane >> 4));
#pragma unroll
      for (int i = 0; i < 4; i++)
#pragma unroll
        for (int j = 0; j < 4; j++)
          acc[i][j] = __builtin_amdgcn_mfma_f32_16x16x32_bf16(af[i], bf[j], acc[i][j], 0, 0, 0);
    }
  }
#pragma unroll
  for (int i = 0; i < 4; i++) {
    int o = m0 + wm + i * 16 + ((lane >> 4) << 2);
    int which = o >> 9, h = (o >> 6) & 7, d0 = o & 63;
#pragma unroll
    for (int j = 0; j < 4; j++) {
      int n = n0 + wn + j * 16 + (lane & 15);
      if (which == 2) {
#pragma unroll
        for (int jj = 0; jj < 4; jj++)
          vv[((size_t)(b * 8 + h) * 64 + d0 + jj) * 2304 + n] = f2bf(acc[i][j][jj]);
      } else {
        float sc = which ? 1.0f : 0.18033688011112042f;  // q: 0.125*log2(e)
        us4 pk;
#pragma unroll
        for (int jj = 0; jj < 4; jj++) pk[jj] = f2bf(acc[i][j][jj] * sc);
        unsigned short* dst = (which ? kT : qT) + ((size_t)(b * 8 + h) * 2304 + n) * 64 + d0;
        *(us4*)dst = pk;
      }
    }
  }
}

// ---------------- flash attention (swapped 32x32 MFMA, 64 q-rows/wave, j-split, dbuf) ----------------
// Block: 256 thr = 4 waves = 2 rh x 2 jh; each wave owns TWO 32-row q-blocks (QBLK=128).
// K/V fragments read once per tile feed BOTH q-blocks (2x MFMA per LDS byte vs R6).
// Double-buffered K/V (64KB LDS), one __syncthreads per tile. exp2 direct (scores bounded).
__global__ __launch_bounds__(256, 2) void k_attn(
    const unsigned short* __restrict__ qT, const unsigned short* __restrict__ kT,
    const unsigned short* __restrict__ vv, unsigned short* __restrict__ o2T) {
  __shared__ unsigned short L[2][4][4096];  // [buf][K0,K1,V0,V1][64x64]
  int tid = threadIdx.x, lane = tid & 63;
  int wid = tid >> 6, rh = wid & 1, jh = wid >> 1;
  int il = lane & 31, g = lane >> 5;
  // bijective XCD swizzle: 576 = 8 x 72; per XCD: 4 bh x 18 i-tiles
  int lin = blockIdx.x;
  int xcd = lin & 7, idx = lin >> 3;  // idx in [0,72)
  int bh = xcd * 4 + idx / 18;
  int i0 = (idx % 18) * 128;
  const unsigned short* kT_bh = kT + (size_t)bh * 2304 * 64;
  const unsigned short* vv_bh = vv + (size_t)bh * 64 * 2304;
  // Q fragments direct from global (one-time); two q-blocks per wave
  bf16x8 qfA[4], qfB[4];
  {
    const unsigned short* qrowA = qT + ((size_t)bh * 2304 + i0 + rh * 64 + il) * 64;
    const unsigned short* qrowB = qrowA + 32 * 64;
#pragma unroll
    for (int ks = 0; ks < 4; ks++) {
      qfA[ks] = *(const bf16x8*)(qrowA + (ks * 2 + g) * 8);
      qfB[ks] = *(const bf16x8*)(qrowB + (ks * 2 + g) * 8);
    }
  }

  // ---- hoisted staging addresses (R5-verified: 2 chunk-sets, 8 GLL/STAGE) ----
  int cA = tid, cB = tid + 256;
  int rA = cA >> 3, rB = cB >> 3;
  unsigned swA = (unsigned)(((cA & 7) ^ (rA & 7)) << 3);
  unsigned swB = (unsigned)(((cB & 7) ^ (rB & 7)) << 3);
  unsigned oKA = rA * 64 + swA, oKB = rB * 64 + swB;      // += 4096 per tile
  unsigned oVA = rA * 2304 + swA, oVB = rB * 2304 + swB;  // += 64 per tile
  int db = (tid & 192) * 8;
  unsigned short* dKA0 = &L[0][0][db];
  unsigned short* dKB0 = &L[0][0][2048 + db];
  unsigned short* dKA1 = &L[0][1][db];
  unsigned short* dKB1 = &L[0][1][2048 + db];
  unsigned short* dVA0 = &L[0][2][db];
  unsigned short* dVB0 = &L[0][2][2048 + db];
  unsigned short* dVA1 = &L[0][3][db];
  unsigned short* dVB1 = &L[0][3][2048 + db];

#define STAGE(boff)                                  \
  do {                                               \
    GLL(kT_bh + oKA, dKA0 + (boff));                 \
    GLL(kT_bh + oKB, dKB0 + (boff));                 \
    GLL(kT_bh + 73728 + oKA, dKA1 + (boff));         \
    GLL(kT_bh + 73728 + oKB, dKB1 + (boff));         \
    GLL(vv_bh + oVA, dVA0 + (boff));                 \
    GLL(vv_bh + oVB, dVB0 + (boff));                 \
    GLL(vv_bh + 1152 + oVA, dVA1 + (boff));          \
    GLL(vv_bh + 1152 + oVB, dVB1 + (boff));          \
    oKA += 4096; oKB += 4096; oVA += 64; oVB += 64;  \
  } while (0)

  // ---- hoisted fragment addresses (buf0; buf1 = +16384 elements, folds to imm) ----
  const unsigned short* fK[8];
  const unsigned short* fV[8];
#pragma unroll
  for (int ks = 0; ks < 4; ks++) {
    int cs = ks * 2 + g;
    int o0 = il * 64 + ((cs ^ (il & 7)) << 3);
    int o1 = (32 + il) * 64 + ((cs ^ (il & 7)) << 3);
    fK[ks] = &L[0][jh][o0];
    fK[4 + ks] = &L[0][jh][o1];
    fV[ks] = &L[0][2 + jh][o0];
    fV[4 + ks] = &L[0][2 + jh][o1];
  }

  float lrunA = 0.f, lrunB = 0.f;
  f32x16 OA0 = {}, OA1 = {}, OB0 = {}, OB1 = {};

// softmax + pack for one q-block's S pair -> words w0/w1, accumulates lsum
#define SOFTMAX_PACK(S0, S1, lsum, w0, w1)                                              \
  do {                                                                                  \
    float a16[16];                                                                      \
    _Pragma("unroll") for (int r = 0; r < 16; r++) {                                    \
      S0[r] = __builtin_amdgcn_exp2f(S0[r]);                                            \
      S1[r] = __builtin_amdgcn_exp2f(S1[r]);                                            \
      a16[r] = S0[r] + S1[r];                                                           \
    }                                                                                   \
    _Pragma("unroll") for (int s = 8; s >= 1; s >>= 1)                                  \
        _Pragma("unroll") for (int r = 0; r < 8; r++) if (r < s) a16[r] += a16[r + s];  \
    lsum += a16[0];                                                                     \
    _Pragma("unroll") for (int m = 0; m < 8; m++) {                                     \
      w0[m] = pack2bf(S0[2 * m], S0[2 * m + 1]);                                        \
      w1[m] = pack2bf(S1[2 * m], S1[2 * m + 1]);                                        \
    }                                                                                   \
  } while (0)

// PV for one q-block: exchange P words across g-halves, 8 MFMAs
#define PV(w0, w1, O0, O1, vf)                                                          \
  do {                                                                                  \
    _Pragma("unroll") for (int ks = 0; ks < 4; ks++) {                                  \
      int a = ks & 1;                                                                   \
      unsigned A0, A1, B0, B1;                                                          \
      if (ks >> 1) { A0 = w1[4 * a]; A1 = w1[4 * a + 1]; B0 = w1[4 * a + 2]; B1 = w1[4 * a + 3]; } \
      else         { A0 = w0[4 * a]; A1 = w0[4 * a + 1]; B0 = w0[4 * a + 2]; B1 = w0[4 * a + 3]; } \
      unsigned send0 = g ? A0 : B0, send1 = g ? A1 : B1;                                \
      unsigned pw0 = __shfl_xor(send0, 32), pw1 = __shfl_xor(send1, 32);                \
      union { unsigned u[4]; bf16x8 v; } F;                                             \
      F.u[0] = g ? pw0 : A0;                                                            \
      F.u[1] = g ? pw1 : A1;                                                            \
      F.u[2] = g ? B0 : pw0;                                                            \
      F.u[3] = g ? B1 : pw1;                                                            \
      O0 = __builtin_amdgcn_mfma_f32_32x32x16_bf16(vf[ks], F.v, O0, 0, 0, 0);           \
      O1 = __builtin_amdgcn_mfma_f32_32x32x16_bf16(vf[4 + ks], F.v, O1, 0, 0, 0);       \
    }                                                                                   \
  } while (0)

#define COMP(boff)                                                                      \
  do {                                                                                  \
    bf16x8 kf[8];                                                                       \
    _Pragma("unroll") for (int q = 0; q < 8; q++) kf[q] = *(const bf16x8*)(fK[q] + (boff)); \
    f32x16 SA0 = {}, SA1 = {}, SB0 = {}, SB1 = {};                                      \
    __builtin_amdgcn_s_setprio(1);                                                      \
    _Pragma("unroll") for (int ks = 0; ks < 4; ks++) {                                  \
      SA0 = __builtin_amdgcn_mfma_f32_32x32x16_bf16(kf[ks], qfA[ks], SA0, 0, 0, 0);     \
      SA1 = __builtin_amdgcn_mfma_f32_32x32x16_bf16(kf[4 + ks], qfA[ks], SA1, 0, 0, 0); \
      SB0 = __builtin_amdgcn_mfma_f32_32x32x16_bf16(kf[ks], qfB[ks], SB0, 0, 0, 0);     \
      SB1 = __builtin_amdgcn_mfma_f32_32x32x16_bf16(kf[4 + ks], qfB[ks], SB1, 0, 0, 0); \
    }                                                                                   \
    __builtin_amdgcn_s_setprio(0);                                                      \
    unsigned wA0[8], wA1[8], wB0[8], wB1[8];                                            \
    SOFTMAX_PACK(SA0, SA1, lrunA, wA0, wA1);                                            \
    SOFTMAX_PACK(SB0, SB1, lrunB, wB0, wB1);                                            \
    bf16x8 vf[8];                                                                       \
    _Pragma("unroll") for (int q = 0; q < 8; q++) vf[q] = *(const bf16x8*)(fV[q] + (boff)); \
    __builtin_amdgcn_s_setprio(1);                                                      \
    PV(wA0, wA1, OA0, OA1, vf);                                                         \
    PV(wB0, wB1, OB0, OB1, vf);                                                         \
    __builtin_amdgcn_s_setprio(0);                                                      \
  } while (0)

  STAGE(0);  // tile 0 -> buf0; offsets advance to tile 1
  __syncthreads();
#pragma unroll 1
  for (int it = 0; it < 9; it++) {
    STAGE(16384);  // tile 2it+1 -> buf1 (in flight across compute)
    COMP(0);       // tile 2it from buf0
    __syncthreads();
    if (it < 8) STAGE(0);  // tile 2it+2 -> buf0
    COMP(16384);           // tile 2it+1 from buf1
    __syncthreads();
  }
#undef STAGE
#undef COMP
#undef SOFTMAX_PACK
#undef PV

  // combine g-halves of l (each half holds partial row-sum for row il)
  lrunA += __shfl_xor(lrunA, 32);
  lrunB += __shfl_xor(lrunB, 32);
  // ---- merge the two jh states through LDS ----
  float* sm = (float*)&L[0][0][0];  // [128][64] f32 = 32KB (buf0)
  float* ml = (float*)&L[1][0][0];  // [128] f32 (buf1)
  if (jh == 1) {
#pragma unroll
    for (int r = 0; r < 16; r++) {
      sm[((rh * 2 + 0) * 32 + r) * 64 + lane] = OA0[r];
      sm[((rh * 2 + 0) * 32 + 16 + r) * 64 + lane] = OA1[r];
      sm[((rh * 2 + 1) * 32 + r) * 64 + lane] = OB0[r];
      sm[((rh * 2 + 1) * 32 + 16 + r) * 64 + lane] = OB1[r];
    }
    if (!g) {
      ml[(rh * 2 + 0) * 32 + il] = lrunA;
      ml[(rh * 2 + 1) * 32 + il] = lrunB;
    }
  }
  __syncthreads();
  if (jh == 0) {
    int b = bh >> 3, h = bh & 7;
#pragma unroll
    for (int qb = 0; qb < 2; qb++) {
      float lr = qb ? lrunB : lrunA;
      float rl = 1.0f / (lr + ml[(rh * 2 + qb) * 32 + il]);
      unsigned short* dst =
          o2T + ((size_t)b * 2304 + (i0 + rh * 64 + qb * 32 + il)) * 512 + h * 64;
#pragma unroll
      for (int dt = 0; dt < 2; dt++) {
#pragma unroll
        for (int u = 0; u < 4; u++) {
          us4 pk;
#pragma unroll
          for (int v = 0; v < 4; v++) {
            int r = 4 * u + v;
            float own = qb ? (dt ? OB1[r] : OB0[r]) : (dt ? OA1[r] : OA0[r]);
            float oth = sm[((rh * 2 + qb) * 32 + dt * 16 + r) * 64 + lane];
            pk[v] = f2bf((own + oth) * rl);
          }
          *(us4*)(dst + dt * 32 + 8 * u + 4 * g) = pk;
        }
      }
    }
  }
}

// ---------------- GEMM2: out = Wout * out2 + bout ----------------
__global__ __launch_bounds__(256, 2) void k_gemm_out(
    const unsigned short* __restrict__ Wo, const unsigned short* __restrict__ o2T,
    const float* __restrict__ bout, float* __restrict__ out) {
  __shared__ unsigned short As[128 * 64];
  __shared__ unsigned short Bs[128 * 64];
  int tid = threadIdx.x, lane = tid & 63, wid = tid >> 6;
  int m0 = blockIdx.x * 128, n0 = blockIdx.y * 128, b = blockIdx.z;
  const unsigned short* Ag = Wo + (size_t)m0 * 512;
  const unsigned short* Bg = o2T + ((size_t)b * 2304 + n0) * 512;
  int wm = (wid >> 1) * 64, wn = (wid & 1) * 64;
  f32x4 acc[4][4] = {};
  for (int kt = 0; kt < 512; kt += 64) {
    __syncthreads();
    stage_chunks(Ag + kt, 512, As, 128, tid);
    stage_chunks(Bg + kt, 512, Bs, 128, tid);
    __syncthreads();
#pragma unroll
    for (int kk = 0; kk < 2; kk++) {
      bf16x8 af[4], bf[4];
#pragma unroll
      for (int i = 0; i < 4; i++) af[i] = frag(As, wm + i * 16 + (lane & 15), kk * 4 + (lane >> 4));
#pragma unroll
      for (int j = 0; j < 4; j++) bf[j] = frag(Bs, wn + j * 16 + (lane & 15), kk * 4 + (lane >> 4));
#pragma unroll
      for (int i = 0; i < 4; i++)
#pragma unroll
        for (int j = 0; j < 4; j++)
          acc[i][j] = __builtin_amdgcn_mfma_f32_16x16x32_bf16(af[i], bf[j], acc[i][j], 0, 0, 0);
    }
  }
#pragma unroll
  for (int i = 0; i < 4; i++) {
    int c = m0 + wm + i * 16 + ((lane >> 4) << 2);
#pragma unroll
    for (int j = 0; j < 4; j++) {
      int n = n0 + wn + j * 16 + (lane & 15);
#pragma unroll
      for (int jj = 0; jj < 4; jj++)
        out[((size_t)b * 256 + c + jj) * 2304 + n] = acc[i][j][jj] + bout[c + jj];
    }
  }
}

extern "C" void kernel_launch(void* const* d_in, const int* in_sizes, int n_in,
                              void* d_out, int out_size, void* d_ws, size_t ws_size,
                              hipStream_t stream) {
  const float* x = (const float*)d_in[0];
  const float* Wqkv = (const float*)d_in[1];
  const float* Wout = (const float*)d_in[2];
  const float* bout = (const float*)d_in[3];
  float* out = (float*)d_out;
  char* ws = (char*)d_ws;
  unsigned short* Wqkv_bf = (unsigned short*)(ws + 0);          //  786432
  unsigned short* Wout_bf = (unsigned short*)(ws + 786432);     //  262144
  unsigned short* xT      = (unsigned short*)(ws + 1048576);    // 4718592
  unsigned short* qT      = (unsigned short*)(ws + 5767168);    // 9437184
  unsigned short* kT      = (unsigned short*)(ws + 15204352);   // 9437184
  unsigned short* vv      = (unsigned short*)(ws + 24641536);   // 9437184
  unsigned short* o2T     = (unsigned short*)(ws + 34078720);   // 9437184 (end 43515904)

  k_cvt<<<dim3(384), dim3(256), 0, stream>>>(Wqkv, Wqkv_bf, 1536 * 256);
  k_cvt<<<dim3(128), dim3(256), 0, stream>>>(Wout, Wout_bf, 256 * 512);
  k_xpose<<<dim3(72, 8, 4), dim3(256), 0, stream>>>(x, xT);
  k_gemm_qkv<<<dim3(12, 18, 4), dim3(256), 0, stream>>>(Wqkv_bf, xT, qT, kT, vv);
  k_attn<<<dim3(576), dim3(256), 0, stream>>>(qT, kT, vv, o2T);
  k_gemm_out<<<dim3(2, 18, 4), dim3(256), 0, stream>>>(Wout_bf, o2T, bout, out);
}

// Round 10
// 112.668 us; speedup vs baseline: 1.0347x; 1.0347x over previous
//
#include <hip/hip_runtime.h>

typedef __attribute__((ext_vector_type(8))) __bf16 bf16x8;
typedef __attribute__((ext_vector_type(16))) float f32x16;
typedef __attribute__((ext_vector_type(4))) float f32x4;
typedef __attribute__((ext_vector_type(4))) unsigned short us4;

__device__ __forceinline__ unsigned short f2bf(float f) {
  __bf16 h = (__bf16)f;  // native RNE convert
  return __builtin_bit_cast(unsigned short, h);
}
__device__ __forceinline__ unsigned pack2bf(float lo, float hi) {
  return (unsigned)f2bf(lo) | ((unsigned)f2bf(hi) << 16);
}

#define GLL(src, dst)                                                            \
  __builtin_amdgcn_global_load_lds((const __attribute__((address_space(1))) void*)(src), \
                                   (__attribute__((address_space(3))) void*)(dst), 16, 0, 0)

// Stage a [rows x 64] bf16 tile (row-major, row stride = ld elements in global)
// into LDS with 16B-chunk XOR swizzle: LDS(row, kc) = G(row, kc ^ (row&7)).
__device__ __forceinline__ void stage_chunks(const unsigned short* g, int ld,
                                             unsigned short* lds, int rows, int tid) {
  int total = rows * 8;  // 16B chunks
  for (int c0 = 0; c0 < total; c0 += 256) {
    int c = c0 + tid;
    int row = c >> 3, kc = c & 7;
    const unsigned short* src = g + (size_t)row * ld + ((kc ^ (row & 7)) << 3);
    unsigned short* dst = lds + (size_t)(c0 + (tid & 192)) * 8;  // wave-uniform base
    GLL(src, dst);
  }
}

// Read one MFMA fragment (8 contiguous bf16 = 16B) from a swizzled [*x64] tile.
__device__ __forceinline__ bf16x8 frag(const unsigned short* lds, int row, int kc) {
  return *(const bf16x8*)(lds + row * 64 + ((kc ^ (row & 7)) << 3));
}

// ---------------- converts / transpose ----------------

__global__ void k_cvt(const float* __restrict__ in, unsigned short* __restrict__ outp, int n) {
  int i = (blockIdx.x * 256 + threadIdx.x) * 4;
  if (i + 3 < n) {
    f32x4 v = *(const f32x4*)(in + i);
    us4 o;
#pragma unroll
    for (int k = 0; k < 4; k++) o[k] = f2bf(v[k]);
    *(us4*)(outp + i) = o;
  }
}

// xT[b][n][c] = x[b][c][n], fp32 -> bf16
__global__ __launch_bounds__(256) void k_xpose(const float* __restrict__ x,
                                               unsigned short* __restrict__ xT) {
  __shared__ float t[32][33];
  int tid = threadIdx.x;
  int col = tid & 31, rowb = tid >> 5;
  int nt = blockIdx.x * 32, ct = blockIdx.y * 32, b = blockIdx.z;
  const float* src = x + ((size_t)b * 256 + ct) * 2304 + nt;
#pragma unroll
  for (int rr = 0; rr < 32; rr += 8) t[rowb + rr][col] = src[(size_t)(rowb + rr) * 2304 + col];
  __syncthreads();
  unsigned short* dst = xT + ((size_t)b * 2304 + nt) * 256 + ct;
#pragma unroll
  for (int rr = 0; rr < 32; rr += 8) dst[(size_t)(rowb + rr) * 256 + col] = f2bf(t[col][rowb + rr]);
}

// ---------------- GEMM1: qkv = Wqkv * x ----------------
// q is pre-scaled by 0.125 * log2(e) so attention can use exp2 directly.
__global__ __launch_bounds__(256, 2) void k_gemm_qkv(
    const unsigned short* __restrict__ W, const unsigned short* __restrict__ xT,
    unsigned short* __restrict__ qT, unsigned short* __restrict__ kT,
    unsigned short* __restrict__ vv) {
  __shared__ unsigned short As[128 * 64];
  __shared__ unsigned short Bs[128 * 64];
  int tid = threadIdx.x, lane = tid & 63, wid = tid >> 6;
  int m0 = blockIdx.x * 128, n0 = blockIdx.y * 128, b = blockIdx.z;
  const unsigned short* Ag = W + (size_t)m0 * 256;
  const unsigned short* Bg = xT + ((size_t)b * 2304 + n0) * 256;
  int wm = (wid >> 1) * 64, wn = (wid & 1) * 64;
  f32x4 acc[4][4] = {};
  for (int kt = 0; kt < 256; kt += 64) {
    __syncthreads();
    stage_chunks(Ag + kt, 256, As, 128, tid);
    stage_chunks(Bg + kt, 256, Bs, 128, tid);
    __syncthreads();
#pragma unroll
    for (int kk = 0; kk < 2; kk++) {
      bf16x8 af[4], bf[4];
#pragma unroll
      for (int i = 0; i < 4; i++) af[i] = frag(As, wm + i * 16 + (lane & 15), kk * 4 + (lane >> 4));
#pragma unroll
      for (int j = 0; j < 4; j++) bf[j] = frag(Bs, wn + j * 16 + (lane & 15), kk * 4 + (lane >> 4));
#pragma unroll
      for (int i = 0; i < 4; i++)
#pragma unroll
        for (int j = 0; j < 4; j++)
          acc[i][j] = __builtin_amdgcn_mfma_f32_16x16x32_bf16(af[i], bf[j], acc[i][j], 0, 0, 0);
    }
  }
#pragma unroll
  for (int i = 0; i < 4; i++) {
    int o = m0 + wm + i * 16 + ((lane >> 4) << 2);
    int which = o >> 9, h = (o >> 6) & 7, d0 = o & 63;
#pragma unroll
    for (int j = 0; j < 4; j++) {
      int n = n0 + wn + j * 16 + (lane & 15);
      if (which == 2) {
#pragma unroll
        for (int jj = 0; jj < 4; jj++)
          vv[((size_t)(b * 8 + h) * 64 + d0 + jj) * 2304 + n] = f2bf(acc[i][j][jj]);
      } else {
        float sc = which ? 1.0f : 0.18033688011112042f;  // q: 0.125*log2(e)
        us4 pk;
#pragma unroll
        for (int jj = 0; jj < 4; jj++) pk[jj] = f2bf(acc[i][j][jj] * sc);
        unsigned short* dst = (which ? kT : qT) + ((size_t)(b * 8 + h) * 2304 + n) * 64 + d0;
        *(us4*)dst = pk;
      }
    }
  }
}

// ---------------- flash attention (swapped 32x32 MFMA, within-tile j-split, dbuf) ----------------
// Block: 256 thr = 4 waves = 2 rh x 2 jh. QBLK=64. Per step stage ONE 64-row KV tile
// (K 8KB + V 8KB); jh=0 processes j-rows 0-31, jh=1 rows 32-63 of the SAME tile.
// LDS = 32KB dbuf -> 4-5 blocks/CU (vs 2 at 64KB). 36 steps. exp2 direct (scores bounded).
__global__ __launch_bounds__(256, 4) void k_attn(
    const unsigned short* __restrict__ qT, const unsigned short* __restrict__ kT,
    const unsigned short* __restrict__ vv, unsigned short* __restrict__ o2T) {
  __shared__ unsigned short L[2][2][4096];  // [buf][K,V][64x64]
  int tid = threadIdx.x, lane = tid & 63;
  int wid = tid >> 6, rh = wid & 1, jh = wid >> 1;
  int il = lane & 31, g = lane >> 5;
  // bijective XCD swizzle: 1152 = 8 x 144; per XCD: 4 bh x 36 i-tiles
  int lin = blockIdx.x;
  int xcd = lin & 7, idx = lin >> 3;  // idx in [0,144)
  int bh = xcd * 4 + idx / 36;
  int i0 = (idx % 36) * 64;
  const unsigned short* kT_bh = kT + (size_t)bh * 2304 * 64;
  const unsigned short* vv_bh = vv + (size_t)bh * 64 * 2304;
  // Q fragments direct from global (one-time)
  const unsigned short* qrow = qT + ((size_t)bh * 2304 + i0 + rh * 32 + il) * 64;
  bf16x8 qf[4];
#pragma unroll
  for (int ks = 0; ks < 4; ks++) qf[ks] = *(const bf16x8*)(qrow + (ks * 2 + g) * 8);

  // ---- hoisted staging addresses (2 chunk-sets each for K and V; 4 GLL/STAGE) ----
  int cA = tid, cB = tid + 256;
  int rA = cA >> 3, rB = cB >> 3;
  unsigned swA = (unsigned)(((cA & 7) ^ (rA & 7)) << 3);
  unsigned swB = (unsigned)(((cB & 7) ^ (rB & 7)) << 3);
  unsigned oKA = rA * 64 + swA, oKB = rB * 64 + swB;      // += 4096 per tile
  unsigned oVA = rA * 2304 + swA, oVB = rB * 2304 + swB;  // += 64 per tile
  int db = (tid & 192) * 8;
  unsigned short* dKA = &L[0][0][db];
  unsigned short* dKB = &L[0][0][2048 + db];
  unsigned short* dVA = &L[0][1][db];
  unsigned short* dVB = &L[0][1][2048 + db];

#define STAGE(boff)                          \
  do {                                       \
    GLL(kT_bh + oKA, dKA + (boff));          \
    GLL(kT_bh + oKB, dKB + (boff));          \
    GLL(vv_bh + oVA, dVA + (boff));          \
    GLL(vv_bh + oVB, dVB + (boff));          \
    oKA += 4096; oKB += 4096; oVA += 64; oVB += 64; \
  } while (0)

  // ---- hoisted fragment addresses (buf0; buf1 = +8192 elements, folds to imm) ----
  // K: A-operand rows jh*32+il, d-slice cs = ks*2+g (ks 0..3)
  const unsigned short* fK[4];
  // V: A-operand rows d = dblk*32+il, j-slice cs' = jh*4 + ks*2 + g (ks 0..1, dblk 0..1)
  const unsigned short* fV[4];
#pragma unroll
  for (int ks = 0; ks < 4; ks++) {
    int cs = ks * 2 + g;
    fK[ks] = &L[0][0][(jh * 32 + il) * 64 + ((cs ^ (il & 7)) << 3)];
  }
#pragma unroll
  for (int ks = 0; ks < 2; ks++)
#pragma unroll
    for (int dblk = 0; dblk < 2; dblk++) {
      int cs = jh * 4 + ks * 2 + g;
      fV[ks * 2 + dblk] = &L[0][1][(dblk * 32 + il) * 64 + ((cs ^ (il & 7)) << 3)];
    }

  float lrun = 0.f;
  f32x16 O0 = {}, O1 = {};

#define COMP(boff)                                                                      \
  do {                                                                                  \
    bf16x8 kf[4];                                                                       \
    _Pragma("unroll") for (int q = 0; q < 4; q++) kf[q] = *(const bf16x8*)(fK[q] + (boff)); \
    f32x16 S0 = {};                                                                     \
    __builtin_amdgcn_s_setprio(1);                                                      \
    _Pragma("unroll") for (int ks = 0; ks < 4; ks++)                                    \
      S0 = __builtin_amdgcn_mfma_f32_32x32x16_bf16(kf[ks], qf[ks], S0, 0, 0, 0);        \
    __builtin_amdgcn_s_setprio(0);                                                      \
    float a16[16];                                                                      \
    _Pragma("unroll") for (int r = 0; r < 16; r++) {                                    \
      S0[r] = __builtin_amdgcn_exp2f(S0[r]);                                            \
      a16[r] = S0[r];                                                                   \
    }                                                                                   \
    _Pragma("unroll") for (int s = 8; s >= 1; s >>= 1)                                  \
        _Pragma("unroll") for (int r = 0; r < 8; r++) if (r < s) a16[r] += a16[r + s];  \
    lrun += a16[0];                                                                     \
    unsigned w[8];                                                                      \
    _Pragma("unroll") for (int m = 0; m < 8; m++) w[m] = pack2bf(S0[2 * m], S0[2 * m + 1]); \
    bf16x8 vf[4];                                                                       \
    _Pragma("unroll") for (int q = 0; q < 4; q++) vf[q] = *(const bf16x8*)(fV[q] + (boff)); \
    __builtin_amdgcn_s_setprio(1);                                                      \
    _Pragma("unroll") for (int ks = 0; ks < 2; ks++) {                                  \
      unsigned A0 = w[4 * ks], A1 = w[4 * ks + 1], B0 = w[4 * ks + 2], B1 = w[4 * ks + 3]; \
      unsigned send0 = g ? A0 : B0, send1 = g ? A1 : B1;                                \
      unsigned pw0 = __shfl_xor(send0, 32), pw1 = __shfl_xor(send1, 32);                \
      union { unsigned u[4]; bf16x8 v; } F;                                             \
      F.u[0] = g ? pw0 : A0;                                                            \
      F.u[1] = g ? pw1 : A1;                                                            \
      F.u[2] = g ? B0 : pw0;                                                            \
      F.u[3] = g ? B1 : pw1;                                                            \
      O0 = __builtin_amdgcn_mfma_f32_32x32x16_bf16(vf[ks * 2 + 0], F.v, O0, 0, 0, 0);   \
      O1 = __builtin_amdgcn_mfma_f32_32x32x16_bf16(vf[ks * 2 + 1], F.v, O1, 0, 0, 0);   \
    }                                                                                   \
    __builtin_amdgcn_s_setprio(0);                                                      \
  } while (0)

  STAGE(0);  // tile 0 -> buf0; offsets advance to tile 1
  __syncthreads();
#pragma unroll 1
  for (int it = 0; it < 18; it++) {
    STAGE(8192);  // tile 2it+1 -> buf1 (in flight across compute)
    COMP(0);      // tile 2it from buf0
    __syncthreads();
    if (it < 17) STAGE(0);  // tile 2it+2 -> buf0
    COMP(8192);             // tile 2it+1 from buf1
    __syncthreads();
  }
#undef STAGE
#undef COMP

  // combine g-halves of l (each half holds partial row-sum for row il)
  lrun += __shfl_xor(lrun, 32);
  // ---- merge the two jh states through LDS ----
  float* sm = (float*)&L[0][0][0];  // [64][64] f32 = 16KB
  float* ml = (float*)&L[1][0][0];  // [64] f32
  if (jh == 1) {
#pragma unroll
    for (int r = 0; r < 16; r++) {
      sm[(rh * 32 + r) * 64 + lane] = O0[r];
      sm[(rh * 32 + 16 + r) * 64 + lane] = O1[r];
    }
    if (!g) ml[rh * 32 + il] = lrun;
  }
  __syncthreads();
  if (jh == 0) {
    float rl = 1.0f / (lrun + ml[rh * 32 + il]);
    int b = bh >> 3, h = bh & 7;
    unsigned short* dst = o2T + ((size_t)b * 2304 + (i0 + rh * 32 + il)) * 512 + h * 64;
#pragma unroll
    for (int dt = 0; dt < 2; dt++) {
#pragma unroll
      for (int u = 0; u < 4; u++) {
        us4 pk;
#pragma unroll
        for (int v = 0; v < 4; v++) {
          int r = 4 * u + v;
          float own = dt ? O1[r] : O0[r];
          float oth = sm[(rh * 32 + dt * 16 + r) * 64 + lane];
          pk[v] = f2bf((own + oth) * rl);
        }
        *(us4*)(dst + dt * 32 + 8 * u + 4 * g) = pk;
      }
    }
  }
}

// ---------------- GEMM2: out = Wout * out2 + bout ----------------
__global__ __launch_bounds__(256, 2) void k_gemm_out(
    const unsigned short* __restrict__ Wo, const unsigned short* __restrict__ o2T,
    const float* __restrict__ bout, float* __restrict__ out) {
  __shared__ unsigned short As[128 * 64];
  __shared__ unsigned short Bs[128 * 64];
  int tid = threadIdx.x, lane = tid & 63, wid = tid >> 6;
  int m0 = blockIdx.x * 128, n0 = blockIdx.y * 128, b = blockIdx.z;
  const unsigned short* Ag = Wo + (size_t)m0 * 512;
  const unsigned short* Bg = o2T + ((size_t)b * 2304 + n0) * 512;
  int wm = (wid >> 1) * 64, wn = (wid & 1) * 64;
  f32x4 acc[4][4] = {};
  for (int kt = 0; kt < 512; kt += 64) {
    __syncthreads();
    stage_chunks(Ag + kt, 512, As, 128, tid);
    stage_chunks(Bg + kt, 512, Bs, 128, tid);
    __syncthreads();
#pragma unroll
    for (int kk = 0; kk < 2; kk++) {
      bf16x8 af[4], bf[4];
#pragma unroll
      for (int i = 0; i < 4; i++) af[i] = frag(As, wm + i * 16 + (lane & 15), kk * 4 + (lane >> 4));
#pragma unroll
      for (int j = 0; j < 4; j++) bf[j] = frag(Bs, wn + j * 16 + (lane & 15), kk * 4 + (lane >> 4));
#pragma unroll
      for (int i = 0; i < 4; i++)
#pragma unroll
        for (int j = 0; j < 4; j++)
          acc[i][j] = __builtin_amdgcn_mfma_f32_16x16x32_bf16(af[i], bf[j], acc[i][j], 0, 0, 0);
    }
  }
#pragma unroll
  for (int i = 0; i < 4; i++) {
    int c = m0 + wm + i * 16 + ((lane >> 4) << 2);
#pragma unroll
    for (int j = 0; j < 4; j++) {
      int n = n0 + wn + j * 16 + (lane & 15);
#pragma unroll
      for (int jj = 0; jj < 4; jj++)
        out[((size_t)b * 256 + c + jj) * 2304 + n] = acc[i][j][jj] + bout[c + jj];
    }
  }
}

extern "C" void kernel_launch(void* const* d_in, const int* in_sizes, int n_in,
                              void* d_out, int out_size, void* d_ws, size_t ws_size,
                              hipStream_t stream) {
  const float* x = (const float*)d_in[0];
  const float* Wqkv = (const float*)d_in[1];
  const float* Wout = (const float*)d_in[2];
  const float* bout = (const float*)d_in[3];
  float* out = (float*)d_out;
  char* ws = (char*)d_ws;
  unsigned short* Wqkv_bf = (unsigned short*)(ws + 0);          //  786432
  unsigned short* Wout_bf = (unsigned short*)(ws + 786432);     //  262144
  unsigned short* xT      = (unsigned short*)(ws + 1048576);    // 4718592
  unsigned short* qT      = (unsigned short*)(ws + 5767168);    // 9437184
  unsigned short* kT      = (unsigned short*)(ws + 15204352);   // 9437184
  unsigned short* vv      = (unsigned short*)(ws + 24641536);   // 9437184
  unsigned short* o2T     = (unsigned short*)(ws + 34078720);   // 9437184 (end 43515904)

  k_cvt<<<dim3(384), dim3(256), 0, stream>>>(Wqkv, Wqkv_bf, 1536 * 256);
  k_cvt<<<dim3(128), dim3(256), 0, stream>>>(Wout, Wout_bf, 256 * 512);
  k_xpose<<<dim3(72, 8, 4), dim3(256), 0, stream>>>(x, xT);
  k_gemm_qkv<<<dim3(12, 18, 4), dim3(256), 0, stream>>>(Wqkv_bf, xT, qT, kT, vv);
  k_attn<<<dim3(1152), dim3(256), 0, stream>>>(qT, kT, vv, o2T);
  k_gemm_out<<<dim3(2, 18, 4), dim3(256), 0, stream>>>(Wout_bf, o2T, bout, out);
}

// Round 11
// 112.579 us; speedup vs baseline: 1.0355x; 1.0008x over previous
//
#include <hip/hip_runtime.h>

typedef __attribute__((ext_vector_type(8))) __bf16 bf16x8;
typedef __attribute__((ext_vector_type(16))) float f32x16;
typedef __attribute__((ext_vector_type(4))) float f32x4;
typedef __attribute__((ext_vector_type(4))) unsigned short us4;

__device__ __forceinline__ unsigned short f2bf(float f) {
  __bf16 h = (__bf16)f;  // native RNE convert
  return __builtin_bit_cast(unsigned short, h);
}
__device__ __forceinline__ unsigned pack2bf(float lo, float hi) {
  return (unsigned)f2bf(lo) | ((unsigned)f2bf(hi) << 16);
}

#define GLL(src, dst)                                                            \
  __builtin_amdgcn_global_load_lds((const __attribute__((address_space(1))) void*)(src), \
                                   (__attribute__((address_space(3))) void*)(dst), 16, 0, 0)

// Stage a [rows x 64] bf16 tile (row-major, row stride = ld elements in global)
// into LDS with 16B-chunk XOR swizzle: LDS(row, kc) = G(row, kc ^ (row&7)).
__device__ __forceinline__ void stage_chunks(const unsigned short* g, int ld,
                                             unsigned short* lds, int rows, int tid) {
  int total = rows * 8;  // 16B chunks
  for (int c0 = 0; c0 < total; c0 += 256) {
    int c = c0 + tid;
    int row = c >> 3, kc = c & 7;
    const unsigned short* src = g + (size_t)row * ld + ((kc ^ (row & 7)) << 3);
    unsigned short* dst = lds + (size_t)(c0 + (tid & 192)) * 8;  // wave-uniform base
    GLL(src, dst);
  }
}

// Read one MFMA fragment (8 contiguous bf16 = 16B) from a swizzled [*x64] tile.
__device__ __forceinline__ bf16x8 frag(const unsigned short* lds, int row, int kc) {
  return *(const bf16x8*)(lds + row * 64 + ((kc ^ (row & 7)) << 3));
}

// ---------------- converts / transpose ----------------

__global__ void k_cvt(const float* __restrict__ in, unsigned short* __restrict__ outp, int n) {
  int i = (blockIdx.x * 256 + threadIdx.x) * 4;
  if (i + 3 < n) {
    f32x4 v = *(const f32x4*)(in + i);
    us4 o;
#pragma unroll
    for (int k = 0; k < 4; k++) o[k] = f2bf(v[k]);
    *(us4*)(outp + i) = o;
  }
}

// xT[b][n][c] = x[b][c][n], fp32 -> bf16
__global__ __launch_bounds__(256) void k_xpose(const float* __restrict__ x,
                                               unsigned short* __restrict__ xT) {
  __shared__ float t[32][33];
  int tid = threadIdx.x;
  int col = tid & 31, rowb = tid >> 5;
  int nt = blockIdx.x * 32, ct = blockIdx.y * 32, b = blockIdx.z;
  const float* src = x + ((size_t)b * 256 + ct) * 2304 + nt;
#pragma unroll
  for (int rr = 0; rr < 32; rr += 8) t[rowb + rr][col] = src[(size_t)(rowb + rr) * 2304 + col];
  __syncthreads();
  unsigned short* dst = xT + ((size_t)b * 2304 + nt) * 256 + ct;
#pragma unroll
  for (int rr = 0; rr < 32; rr += 8) dst[(size_t)(rowb + rr) * 256 + col] = f2bf(t[col][rowb + rr]);
}

// ---------------- GEMM1: qkv = Wqkv * x ----------------
// q is pre-scaled by 0.125 * log2(e) so attention can use exp2 directly.
__global__ __launch_bounds__(256, 2) void k_gemm_qkv(
    const unsigned short* __restrict__ W, const unsigned short* __restrict__ xT,
    unsigned short* __restrict__ qT, unsigned short* __restrict__ kT,
    unsigned short* __restrict__ vv) {
  __shared__ unsigned short As[128 * 64];
  __shared__ unsigned short Bs[128 * 64];
  int tid = threadIdx.x, lane = tid & 63, wid = tid >> 6;
  int m0 = blockIdx.x * 128, n0 = blockIdx.y * 128, b = blockIdx.z;
  const unsigned short* Ag = W + (size_t)m0 * 256;
  const unsigned short* Bg = xT + ((size_t)b * 2304 + n0) * 256;
  int wm = (wid >> 1) * 64, wn = (wid & 1) * 64;
  f32x4 acc[4][4] = {};
  for (int kt = 0; kt < 256; kt += 64) {
    __syncthreads();
    stage_chunks(Ag + kt, 256, As, 128, tid);
    stage_chunks(Bg + kt, 256, Bs, 128, tid);
    __syncthreads();
#pragma unroll
    for (int kk = 0; kk < 2; kk++) {
      bf16x8 af[4], bf[4];
#pragma unroll
      for (int i = 0; i < 4; i++) af[i] = frag(As, wm + i * 16 + (lane & 15), kk * 4 + (lane >> 4));
#pragma unroll
      for (int j = 0; j < 4; j++) bf[j] = frag(Bs, wn + j * 16 + (lane & 15), kk * 4 + (lane >> 4));
#pragma unroll
      for (int i = 0; i < 4; i++)
#pragma unroll
        for (int j = 0; j < 4; j++)
          acc[i][j] = __builtin_amdgcn_mfma_f32_16x16x32_bf16(af[i], bf[j], acc[i][j], 0, 0, 0);
    }
  }
#pragma unroll
  for (int i = 0; i < 4; i++) {
    int o = m0 + wm + i * 16 + ((lane >> 4) << 2);
    int which = o >> 9, h = (o >> 6) & 7, d0 = o & 63;
#pragma unroll
    for (int j = 0; j < 4; j++) {
      int n = n0 + wn + j * 16 + (lane & 15);
      if (which == 2) {
#pragma unroll
        for (int jj = 0; jj < 4; jj++)
          vv[((size_t)(b * 8 + h) * 64 + d0 + jj) * 2304 + n] = f2bf(acc[i][j][jj]);
      } else {
        float sc = which ? 1.0f : 0.18033688011112042f;  // q: 0.125*log2(e)
        us4 pk;
#pragma unroll
        for (int jj = 0; jj < 4; jj++) pk[jj] = f2bf(acc[i][j][jj] * sc);
        unsigned short* dst = (which ? kT : qT) + ((size_t)(b * 8 + h) * 2304 + n) * 64 + d0;
        *(us4*)dst = pk;
      }
    }
  }
}

// ---------------- flash attention (swapped 32x32 MFMA, within-tile j-split, dbuf) ----------------
// Block: 256 thr = 4 waves = 2 rh x 2 jh. QBLK=64. Per step stage ONE 64-row KV tile.
// LDS 32KB dbuf. Conflict-free swizzle: chunk = cs ^ ((row + (row>>3)) & 7) -- the
// row>>3 term gives lanes il, il+8, il+16, il+24 DISTINCT chunks (r9's row&7 gave them
// the same chunk -> 4-way bank conflict, 5.3M cycles/dispatch).
__global__ __launch_bounds__(256, 4) void k_attn(
    const unsigned short* __restrict__ qT, const unsigned short* __restrict__ kT,
    const unsigned short* __restrict__ vv, unsigned short* __restrict__ o2T) {
  __shared__ unsigned short L[2][2][4096];  // [buf][K,V][64x64]
  int tid = threadIdx.x, lane = tid & 63;
  int wid = tid >> 6, rh = wid & 1, jh = wid >> 1;
  int il = lane & 31, g = lane >> 5;
  // bijective XCD swizzle: 1152 = 8 x 144; per XCD: 4 bh x 36 i-tiles
  int lin = blockIdx.x;
  int xcd = lin & 7, idx = lin >> 3;  // idx in [0,144)
  int bh = xcd * 4 + idx / 36;
  int i0 = (idx % 36) * 64;
  const unsigned short* kT_bh = kT + (size_t)bh * 2304 * 64;
  const unsigned short* vv_bh = vv + (size_t)bh * 64 * 2304;
  // Q fragments direct from global (one-time)
  const unsigned short* qrow = qT + ((size_t)bh * 2304 + i0 + rh * 32 + il) * 64;
  bf16x8 qf[4];
#pragma unroll
  for (int ks = 0; ks < 4; ks++) qf[ks] = *(const bf16x8*)(qrow + (ks * 2 + g) * 8);

  // ---- hoisted staging addresses (conflict-free swizzle; 4 GLL/STAGE) ----
  int cA = tid, cB = tid + 256;
  int rA = cA >> 3, rB = cB >> 3;
  unsigned swA = (unsigned)((((cA & 7) ^ ((rA + (rA >> 3)) & 7))) << 3);
  unsigned swB = (unsigned)((((cB & 7) ^ ((rB + (rB >> 3)) & 7))) << 3);
  unsigned oKA = rA * 64 + swA, oKB = rB * 64 + swB;      // += 4096 per tile
  unsigned oVA = rA * 2304 + swA, oVB = rB * 2304 + swB;  // += 64 per tile
  int db = (tid & 192) * 8;
  unsigned short* dKA = &L[0][0][db];
  unsigned short* dKB = &L[0][0][2048 + db];
  unsigned short* dVA = &L[0][1][db];
  unsigned short* dVB = &L[0][1][2048 + db];

#define STAGE(boff)                          \
  do {                                       \
    GLL(kT_bh + oKA, dKA + (boff));          \
    GLL(kT_bh + oKB, dKB + (boff));          \
    GLL(vv_bh + oVA, dVA + (boff));          \
    GLL(vv_bh + oVB, dVB + (boff));          \
    oKA += 4096; oKB += 4096; oVA += 64; oVB += 64; \
  } while (0)

  // ---- hoisted fragment addresses (buf0; buf1 = +8192 elements, folds to imm) ----
  // K: A-operand rows jh*32+il, d-slice cs = ks*2+g (ks 0..3)
  const unsigned short* fK[4];
  // V: A-operand rows d = dblk*32+il, j-slice cs' = jh*4 + ks*2 + g (ks 0..1, dblk 0..1)
  const unsigned short* fV[4];
#pragma unroll
  for (int ks = 0; ks < 4; ks++) {
    int cs = ks * 2 + g;
    int row = jh * 32 + il;
    fK[ks] = &L[0][0][row * 64 + (((cs ^ ((row + (row >> 3)) & 7))) << 3)];
  }
#pragma unroll
  for (int ks = 0; ks < 2; ks++)
#pragma unroll
    for (int dblk = 0; dblk < 2; dblk++) {
      int cs = jh * 4 + ks * 2 + g;
      int row = dblk * 32 + il;
      fV[ks * 2 + dblk] = &L[0][1][row * 64 + (((cs ^ ((row + (row >> 3)) & 7))) << 3)];
    }

  float lrun = 0.f;
  f32x16 O0 = {}, O1 = {};

#define COMP(boff)                                                                      \
  do {                                                                                  \
    bf16x8 kf[4];                                                                       \
    _Pragma("unroll") for (int q = 0; q < 4; q++) kf[q] = *(const bf16x8*)(fK[q] + (boff)); \
    f32x16 S0 = {};                                                                     \
    __builtin_amdgcn_s_setprio(1);                                                      \
    _Pragma("unroll") for (int ks = 0; ks < 4; ks++)                                    \
      S0 = __builtin_amdgcn_mfma_f32_32x32x16_bf16(kf[ks], qf[ks], S0, 0, 0, 0);        \
    __builtin_amdgcn_s_setprio(0);                                                      \
    float a16[16];                                                                      \
    _Pragma("unroll") for (int r = 0; r < 16; r++) {                                    \
      S0[r] = __builtin_amdgcn_exp2f(S0[r]);                                            \
      a16[r] = S0[r];                                                                   \
    }                                                                                   \
    _Pragma("unroll") for (int s = 8; s >= 1; s >>= 1)                                  \
        _Pragma("unroll") for (int r = 0; r < 8; r++) if (r < s) a16[r] += a16[r + s];  \
    lrun += a16[0];                                                                     \
    unsigned w[8];                                                                      \
    _Pragma("unroll") for (int m = 0; m < 8; m++) w[m] = pack2bf(S0[2 * m], S0[2 * m + 1]); \
    bf16x8 vf[4];                                                                       \
    _Pragma("unroll") for (int q = 0; q < 4; q++) vf[q] = *(const bf16x8*)(fV[q] + (boff)); \
    __builtin_amdgcn_s_setprio(1);                                                      \
    _Pragma("unroll") for (int ks = 0; ks < 2; ks++) {                                  \
      unsigned A0 = w[4 * ks], A1 = w[4 * ks + 1], B0 = w[4 * ks + 2], B1 = w[4 * ks + 3]; \
      unsigned send0 = g ? A0 : B0, send1 = g ? A1 : B1;                                \
      unsigned pw0 = __shfl_xor(send0, 32), pw1 = __shfl_xor(send1, 32);                \
      union { unsigned u[4]; bf16x8 v; } F;                                             \
      F.u[0] = g ? pw0 : A0;                                                            \
      F.u[1] = g ? pw1 : A1;                                                            \
      F.u[2] = g ? B0 : pw0;                                                            \
      F.u[3] = g ? B1 : pw1;                                                            \
      O0 = __builtin_amdgcn_mfma_f32_32x32x16_bf16(vf[ks * 2 + 0], F.v, O0, 0, 0, 0);   \
      O1 = __builtin_amdgcn_mfma_f32_32x32x16_bf16(vf[ks * 2 + 1], F.v, O1, 0, 0, 0);   \
    }                                                                                   \
    __builtin_amdgcn_s_setprio(0);                                                      \
  } while (0)

  STAGE(0);  // tile 0 -> buf0; offsets advance to tile 1
  __syncthreads();
#pragma unroll 1
  for (int it = 0; it < 18; it++) {
    STAGE(8192);  // tile 2it+1 -> buf1 (in flight across compute)
    COMP(0);      // tile 2it from buf0
    __syncthreads();
    if (it < 17) STAGE(0);  // tile 2it+2 -> buf0
    COMP(8192);             // tile 2it+1 from buf1
    __syncthreads();
  }
#undef STAGE
#undef COMP

  // combine g-halves of l (each half holds partial row-sum for row il)
  lrun += __shfl_xor(lrun, 32);
  // ---- merge the two jh states through LDS ----
  float* sm = (float*)&L[0][0][0];  // [64][64] f32 = 16KB
  float* ml = (float*)&L[1][0][0];  // [64] f32
  if (jh == 1) {
#pragma unroll
    for (int r = 0; r < 16; r++) {
      sm[(rh * 32 + r) * 64 + lane] = O0[r];
      sm[(rh * 32 + 16 + r) * 64 + lane] = O1[r];
    }
    if (!g) ml[rh * 32 + il] = lrun;
  }
  __syncthreads();
  if (jh == 0) {
    float rl = 1.0f / (lrun + ml[rh * 32 + il]);
    int b = bh >> 3, h = bh & 7;
    unsigned short* dst = o2T + ((size_t)b * 2304 + (i0 + rh * 32 + il)) * 512 + h * 64;
#pragma unroll
    for (int dt = 0; dt < 2; dt++) {
#pragma unroll
      for (int u = 0; u < 4; u++) {
        us4 pk;
#pragma unroll
        for (int v = 0; v < 4; v++) {
          int r = 4 * u + v;
          float own = dt ? O1[r] : O0[r];
          float oth = sm[(rh * 32 + dt * 16 + r) * 64 + lane];
          pk[v] = f2bf((own + oth) * rl);
        }
        *(us4*)(dst + dt * 32 + 8 * u + 4 * g) = pk;
      }
    }
  }
}

// ---------------- GEMM2: out = Wout * out2 + bout ----------------
__global__ __launch_bounds__(256, 2) void k_gemm_out(
    const unsigned short* __restrict__ Wo, const unsigned short* __restrict__ o2T,
    const float* __restrict__ bout, float* __restrict__ out) {
  __shared__ unsigned short As[128 * 64];
  __shared__ unsigned short Bs[128 * 64];
  int tid = threadIdx.x, lane = tid & 63, wid = tid >> 6;
  int m0 = blockIdx.x * 128, n0 = blockIdx.y * 128, b = blockIdx.z;
  const unsigned short* Ag = Wo + (size_t)m0 * 512;
  const unsigned short* Bg = o2T + ((size_t)b * 2304 + n0) * 512;
  int wm = (wid >> 1) * 64, wn = (wid & 1) * 64;
  f32x4 acc[4][4] = {};
  for (int kt = 0; kt < 512; kt += 64) {
    __syncthreads();
    stage_chunks(Ag + kt, 512, As, 128, tid);
    stage_chunks(Bg + kt, 512, Bs, 128, tid);
    __syncthreads();
#pragma unroll
    for (int kk = 0; kk < 2; kk++) {
      bf16x8 af[4], bf[4];
#pragma unroll
      for (int i = 0; i < 4; i++) af[i] = frag(As, wm + i * 16 + (lane & 15), kk * 4 + (lane >> 4));
#pragma unroll
      for (int j = 0; j < 4; j++) bf[j] = frag(Bs, wn + j * 16 + (lane & 15), kk * 4 + (lane >> 4));
#pragma unroll
      for (int i = 0; i < 4; i++)
#pragma unroll
        for (int j = 0; j < 4; j++)
          acc[i][j] = __builtin_amdgcn_mfma_f32_16x16x32_bf16(af[i], bf[j], acc[i][j], 0, 0, 0);
    }
  }
#pragma unroll
  for (int i = 0; i < 4; i++) {
    int c = m0 + wm + i * 16 + ((lane >> 4) << 2);
#pragma unroll
    for (int j = 0; j < 4; j++) {
      int n = n0 + wn + j * 16 + (lane & 15);
#pragma unroll
      for (int jj = 0; jj < 4; jj++)
        out[((size_t)b * 256 + c + jj) * 2304 + n] = acc[i][j][jj] + bout[c + jj];
    }
  }
}

extern "C" void kernel_launch(void* const* d_in, const int* in_sizes, int n_in,
                              void* d_out, int out_size, void* d_ws, size_t ws_size,
                              hipStream_t stream) {
  const float* x = (const float*)d_in[0];
  const float* Wqkv = (const float*)d_in[1];
  const float* Wout = (const float*)d_in[2];
  const float* bout = (const float*)d_in[3];
  float* out = (float*)d_out;
  char* ws = (char*)d_ws;
  unsigned short* Wqkv_bf = (unsigned short*)(ws + 0);          //  786432
  unsigned short* Wout_bf = (unsigned short*)(ws + 786432);     //  262144
  unsigned short* xT      = (unsigned short*)(ws + 1048576);    // 4718592
  unsigned short* qT      = (unsigned short*)(ws + 5767168);    // 9437184
  unsigned short* kT      = (unsigned short*)(ws + 15204352);   // 9437184
  unsigned short* vv      = (unsigned short*)(ws + 24641536);   // 9437184
  unsigned short* o2T     = (unsigned short*)(ws + 34078720);   // 9437184 (end 43515904)

  k_cvt<<<dim3(384), dim3(256), 0, stream>>>(Wqkv, Wqkv_bf, 1536 * 256);
  k_cvt<<<dim3(128), dim3(256), 0, stream>>>(Wout, Wout_bf, 256 * 512);
  k_xpose<<<dim3(72, 8, 4), dim3(256), 0, stream>>>(x, xT);
  k_gemm_qkv<<<dim3(12, 18, 4), dim3(256), 0, stream>>>(Wqkv_bf, xT, qT, kT, vv);
  k_attn<<<dim3(1152), dim3(256), 0, stream>>>(qT, kT, vv, o2T);
  k_gemm_out<<<dim3(2, 18, 4), dim3(256), 0, stream>>>(Wout_bf, o2T, bout, out);
}